// Round 1
// baseline (3234.986 us; speedup 1.0000x reference)
//
#include <hip/hip_runtime.h>

#define ALPHA_SLOPE 0.2f
constexpr int Bb = 2, Nn = 2048, Ff = 768, Hh = 8, Oo = 256;

// ---------------- block reductions (256 threads, 4 waves) ----------------
__device__ inline float block_max256(float v) {
    for (int off = 32; off; off >>= 1) v = fmaxf(v, __shfl_down(v, off, 64));
    __shared__ float w[4];
    int lane = threadIdx.x & 63, wid = threadIdx.x >> 6;
    if (!lane) w[wid] = v;
    __syncthreads();
    float r = fmaxf(fmaxf(w[0], w[1]), fmaxf(w[2], w[3]));
    __syncthreads();
    return r;
}

__device__ inline float block_sum256(float v) {
    for (int off = 32; off; off >>= 1) v += __shfl_down(v, off, 64);
    __shared__ float w[4];
    int lane = threadIdx.x & 63, wid = threadIdx.x >> 6;
    if (!lane) w[wid] = v;
    __syncthreads();
    float r = w[0] + w[1] + w[2] + w[3];
    __syncthreads();
    return r;
}

// ---------------- kernel A: h[b,hd,n,o] = sum_f x[b,n,f] * W[hd,f,o] ----------------
__global__ __launch_bounds__(256) void gemm_xw_kernel(
        const float* __restrict__ x, const float* __restrict__ W, float* __restrict__ h) {
    int z = blockIdx.z;            // b*H + hd
    int b = z >> 3, hd = z & 7;    // H == 8
    const float* A  = x + (size_t)b * Nn * Ff;
    const float* Bm = W + (size_t)hd * Ff * Oo;
    float* C = h + (size_t)z * Nn * Oo;
    int tid = threadIdx.x;
    int tx = tid & 15, ty = tid >> 4;
    int m0 = blockIdx.y * 32, n0 = blockIdx.x * 32;
    __shared__ float As[32][17];
    __shared__ float Bs[16][33];
    float c00 = 0.f, c01 = 0.f, c10 = 0.f, c11 = 0.f;
    for (int k0 = 0; k0 < Ff; k0 += 16) {
        int e = tid, e2 = tid + 256;
        As[e  >> 4][e  & 15] = A[(size_t)(m0 + (e  >> 4)) * Ff + k0 + (e  & 15)];
        As[e2 >> 4][e2 & 15] = A[(size_t)(m0 + (e2 >> 4)) * Ff + k0 + (e2 & 15)];
        int e3 = tid + 256;
        Bs[tid >> 5][tid & 31] = Bm[(size_t)(k0 + (tid >> 5)) * Oo + n0 + (tid & 31)];
        Bs[e3  >> 5][e3  & 31] = Bm[(size_t)(k0 + (e3  >> 5)) * Oo + n0 + (e3  & 31)];
        __syncthreads();
#pragma unroll
        for (int kk = 0; kk < 16; ++kk) {
            float a0 = As[ty][kk], a1 = As[ty + 16][kk];
            float b0 = Bs[kk][tx], b1 = Bs[kk][tx + 16];
            c00 = fmaf(a0, b0, c00); c01 = fmaf(a0, b1, c01);
            c10 = fmaf(a1, b0, c10); c11 = fmaf(a1, b1, c11);
        }
        __syncthreads();
    }
    C[(size_t)(m0 + ty) * Oo + n0 + tx]           = c00;
    C[(size_t)(m0 + ty) * Oo + n0 + tx + 16]      = c01;
    C[(size_t)(m0 + ty + 16) * Oo + n0 + tx]      = c10;
    C[(size_t)(m0 + ty + 16) * Oo + n0 + tx + 16] = c11;
}

// ---------------- generic batched GEMM: C = A * B (or A * B^T), 32x32x16 tiles ----------------
__global__ __launch_bounds__(256) void gemm_g_kernel(
        const float* __restrict__ A, int lda, long long sA,
        const float* __restrict__ Bm, int ldb, long long sB,
        float* __restrict__ C, int ldc, long long sC,
        int K, int transB, const float* __restrict__ bias, int act) {
    int z = blockIdx.z;
    A  += (size_t)z * sA;
    Bm += (size_t)z * sB;
    C  += (size_t)z * sC;
    int tid = threadIdx.x;
    int tx = tid & 15, ty = tid >> 4;
    int m0 = blockIdx.y * 32, n0 = blockIdx.x * 32;
    __shared__ float As[32][17];
    __shared__ float Bs[16][33];
    float c00 = 0.f, c01 = 0.f, c10 = 0.f, c11 = 0.f;
    for (int k0 = 0; k0 < K; k0 += 16) {
        int e = tid, e2 = tid + 256;
        As[e  >> 4][e  & 15] = A[(size_t)(m0 + (e  >> 4)) * lda + k0 + (e  & 15)];
        As[e2 >> 4][e2 & 15] = A[(size_t)(m0 + (e2 >> 4)) * lda + k0 + (e2 & 15)];
        if (!transB) {
            int e3 = tid + 256;
            Bs[tid >> 5][tid & 31] = Bm[(size_t)(k0 + (tid >> 5)) * ldb + n0 + (tid & 31)];
            Bs[e3  >> 5][e3  & 31] = Bm[(size_t)(k0 + (e3  >> 5)) * ldb + n0 + (e3  & 31)];
        } else {
            int n = tid >> 4, k = tid & 15;
            Bs[k][n] = Bm[(size_t)(n0 + n) * ldb + k0 + k];
            int e3 = tid + 256;
            int n2 = e3 >> 4, k2 = e3 & 15;
            Bs[k2][n2] = Bm[(size_t)(n0 + n2) * ldb + k0 + k2];
        }
        __syncthreads();
#pragma unroll
        for (int kk = 0; kk < 16; ++kk) {
            float a0 = As[ty][kk], a1 = As[ty + 16][kk];
            float b0 = Bs[kk][tx], b1 = Bs[kk][tx + 16];
            c00 = fmaf(a0, b0, c00); c01 = fmaf(a0, b1, c01);
            c10 = fmaf(a1, b0, c10); c11 = fmaf(a1, b1, c11);
        }
        __syncthreads();
    }
    float b0v = bias ? bias[n0 + tx] : 0.f;
    float b1v = bias ? bias[n0 + tx + 16] : 0.f;
    c00 += b0v; c01 += b1v; c10 += b0v; c11 += b1v;
    if (act) {
        c00 = fmaxf(c00, 0.f); c01 = fmaxf(c01, 0.f);
        c10 = fmaxf(c10, 0.f); c11 = fmaxf(c11, 0.f);
    }
    C[(size_t)(m0 + ty) * ldc + n0 + tx]           = c00;
    C[(size_t)(m0 + ty) * ldc + n0 + tx + 16]      = c01;
    C[(size_t)(m0 + ty + 16) * ldc + n0 + tx]      = c10;
    C[(size_t)(m0 + ty + 16) * ldc + n0 + tx + 16] = c11;
}

// ---------------- scores: s1[row] = h[row,:]·a[head,:O], s2 = h[row,:]·a[head,O:] ----------------
// one wave per row, 4 rows per block. O = 256 fixed (64 lanes x float4).
__global__ __launch_bounds__(256) void scores_kernel(
        const float* __restrict__ h, const float* __restrict__ a,
        float* __restrict__ s1, float* __restrict__ s2, int NperH, int H) {
    int tid = threadIdx.x;
    int lane = tid & 63, wv = tid >> 6;
    long long row = (long long)blockIdx.x * 4 + wv;
    int head = (int)((row / NperH) % H);
    const float* ap = a + (size_t)head * 2 * Oo;
    float4 x4 = ((const float4*)(h + (size_t)row * Oo))[lane];
    float4 a1 = ((const float4*)ap)[lane];
    float4 a2 = ((const float4*)(ap + Oo))[lane];
    float t1 = x4.x * a1.x + x4.y * a1.y + x4.z * a1.z + x4.w * a1.w;
    float t2 = x4.x * a2.x + x4.y * a2.y + x4.z * a2.z + x4.w * a2.w;
    for (int off = 32; off; off >>= 1) {
        t1 += __shfl_down(t1, off, 64);
        t2 += __shfl_down(t2, off, 64);
    }
    if (!lane) { s1[row] = t1; s2[row] = t2; }
}

// ---------------- masked-softmax attention row: out = softmax_j(mask(leaky(s1_i+s2_j))) @ h ----------------
// One block per (bh, i). 256 threads; thread owns output column o = tid.
__global__ __launch_bounds__(256) void attn_kernel(
        const float* __restrict__ hsrc, const float* __restrict__ adj,
        const float* __restrict__ s1, const float* __restrict__ s2,
        const float* __restrict__ resid, const float* __restrict__ bias,
        float* __restrict__ out, int H, int elu_flag) {
    int i = blockIdx.x;
    int bh = blockIdx.y;
    int b = bh / H, hd = bh - b * H;
    int tid = threadIdx.x;
    const float* adjrow = adj + ((size_t)b * Nn + i) * Nn;
    const float* s2row  = s2 + (size_t)bh * Nn;
    float s1i = s1[(size_t)bh * Nn + i];
    // phase A: masked max of e over j
    float m = -__builtin_inff();
    for (int j = tid; j < Nn; j += 256) {
        float e = s1i + s2row[j];
        e = e > 0.f ? e : ALPHA_SLOPE * e;
        if (adjrow[j] > 0.f) m = fmaxf(m, e);
    }
    m = block_max256(m);
    // phase B: accumulate p_j * h[j, o] with p staged in LDS per 256-j chunk
    __shared__ float ps[256];
    const float* hb = hsrc + (size_t)bh * Nn * Oo;
    float acc = 0.f, lloc = 0.f;
    int o = tid;
    for (int c = 0; c < Nn; c += 256) {
        int j = c + tid;
        float e = s1i + s2row[j];
        e = e > 0.f ? e : ALPHA_SLOPE * e;
        float p = adjrow[j] > 0.f ? __expf(e - m) : 0.f;
        ps[tid] = p;
        lloc += p;
        __syncthreads();
        const float* hc = hb + (size_t)c * Oo + o;
#pragma unroll 8
        for (int jj = 0; jj < 256; ++jj) acc = fmaf(ps[jj], hc[(size_t)jj * Oo], acc);
        __syncthreads();
    }
    float l = block_sum256(lloc);
    float r = acc / l;
    if (elu_flag) r = r > 0.f ? r : expm1f(r);
    if (resid) r += resid[((size_t)b * Nn + i) * Oo + o] + bias[o];
    out[((size_t)b * Nn + i) * ((size_t)H * Oo) + (size_t)hd * Oo + o] = r;
}

extern "C" void kernel_launch(void* const* d_in, const int* in_sizes, int n_in,
                              void* d_out, int out_size, void* d_ws, size_t ws_size,
                              hipStream_t stream) {
    const float* x       = (const float*)d_in[0];
    const float* adj     = (const float*)d_in[1];
    // d_in[2] = mask, unused by the reference forward
    const float* W_heads = (const float*)d_in[3];
    const float* a_heads = (const float*)d_in[4];
    const float* W_out   = (const float*)d_in[5];
    const float* a_out   = (const float*)d_in[6];
    const float* W_lin   = (const float*)d_in[7];
    const float* b_lin   = (const float*)d_in[8];
    const float* W_ln    = (const float*)d_in[9];
    const float* b_ln    = (const float*)d_in[10];

    float* f   = (float*)d_ws;
    float* s1  = f;                      // [B*H*N]   32768
    float* s2  = f + 32768;              // [B*H*N]   32768
    float* s1b = f + 65536;              // [B*N]     4096
    float* s2b = f + 69632;              // [B*N]     4096
    float* x1  = f + 73728;              // [B,N,H*O] 8388608
    float* h   = f + 73728 + 8388608;    // [B,H,N,O] 8388608
    // h is dead after the multihead attention -> reuse its region:
    float* h2  = h;                      // [B,N,O] 1048576
    float* lin = h + 1048576;            // [B,N,O] 1048576
    float* x2  = h + 2097152;            // [B,N,O] 1048576

    // 1) h = x @ W_heads  (per b,head)
    gemm_xw_kernel<<<dim3(Oo / 32, Nn / 32, Bb * Hh), 256, 0, stream>>>(x, W_heads, h);
    // 2) s1, s2
    scores_kernel<<<(Bb * Hh * Nn) / 4, 256, 0, stream>>>(h, a_heads, s1, s2, Nn, Hh);
    // 3) multihead attention + elu, concat heads -> x1 [B,N,H*O]
    attn_kernel<<<dim3(Nn, Bb * Hh), 256, 0, stream>>>(h, adj, s1, s2, nullptr, nullptr, x1, Hh, 1);
    // 4) h2 = x1 @ W_out   [B,N,2048]x[2048,256]
    gemm_g_kernel<<<dim3(Oo / 32, Nn / 32, Bb), 256, 0, stream>>>(
        x1, Hh * Oo, (long long)Nn * Hh * Oo, W_out, Oo, 0,
        h2, Oo, (long long)Nn * Oo, Hh * Oo, 0, nullptr, 0);
    // 5) lin = x1 @ W_lin^T   (W_lin is [O, H*O])
    gemm_g_kernel<<<dim3(Oo / 32, Nn / 32, Bb), 256, 0, stream>>>(
        x1, Hh * Oo, (long long)Nn * Hh * Oo, W_lin, Hh * Oo, 0,
        lin, Oo, (long long)Nn * Oo, Hh * Oo, 1, nullptr, 0);
    // 6) s1b, s2b from h2 with a_out
    scores_kernel<<<(Bb * Nn) / 4, 256, 0, stream>>>(h2, a_out, s1b, s2b, Nn, 1);
    // 7) single-head attention + residual(lin + b_lin) -> x2
    attn_kernel<<<dim3(Nn, Bb), 256, 0, stream>>>(h2, adj, s1b, s2b, lin, b_lin, x2, 1, 0);
    // 8) out = relu(x2 @ W_ln^T + b_ln)
    gemm_g_kernel<<<dim3(Oo / 32, Nn / 32, Bb), 256, 0, stream>>>(
        x2, Oo, (long long)Nn * Oo, W_ln, Oo, 0,
        (float*)d_out, Oo, (long long)Nn * Oo, Oo, 1, b_ln, 1);
}

// Round 2
// 1549.340 us; speedup vs baseline: 2.0880x; 2.0880x over previous
//
#include <hip/hip_runtime.h>

#define ALPHA_SLOPE 0.2f
constexpr int Bb = 2, Nn = 2048, Ff = 768, Hh = 8, Oo = 256;
constexpr int TI = 16;    // i-rows per attention block
constexpr int CJ = 128;   // j-chunk length

// ---------------- adjacency bitmask: bits[b*N+i][j/64] ----------------
__global__ __launch_bounds__(256) void adjbits_kernel(
        const float* __restrict__ adj, unsigned long long* __restrict__ bits) {
    size_t gid = (size_t)blockIdx.x * 256 + threadIdx.x;
    float v = adj[gid];
    unsigned long long m = __ballot(v > 0.f);
    if ((threadIdx.x & 63) == 0) bits[gid >> 6] = m;
}

// ---------------- kernel A: h[b,hd,n,o] = sum_f x[b,n,f] * W[hd,f,o] ----------------
__global__ __launch_bounds__(256) void gemm_xw_kernel(
        const float* __restrict__ x, const float* __restrict__ W, float* __restrict__ h) {
    int z = blockIdx.z;            // b*H + hd
    int b = z >> 3, hd = z & 7;    // H == 8
    const float* A  = x + (size_t)b * Nn * Ff;
    const float* Bm = W + (size_t)hd * Ff * Oo;
    float* C = h + (size_t)z * Nn * Oo;
    int tid = threadIdx.x;
    int tx = tid & 15, ty = tid >> 4;
    int m0 = blockIdx.y * 32, n0 = blockIdx.x * 32;
    __shared__ float As[32][17];
    __shared__ float Bs[16][33];
    float c00 = 0.f, c01 = 0.f, c10 = 0.f, c11 = 0.f;
    for (int k0 = 0; k0 < Ff; k0 += 16) {
        int e = tid, e2 = tid + 256;
        As[e  >> 4][e  & 15] = A[(size_t)(m0 + (e  >> 4)) * Ff + k0 + (e  & 15)];
        As[e2 >> 4][e2 & 15] = A[(size_t)(m0 + (e2 >> 4)) * Ff + k0 + (e2 & 15)];
        int e3 = tid + 256;
        Bs[tid >> 5][tid & 31] = Bm[(size_t)(k0 + (tid >> 5)) * Oo + n0 + (tid & 31)];
        Bs[e3  >> 5][e3  & 31] = Bm[(size_t)(k0 + (e3  >> 5)) * Oo + n0 + (e3  & 31)];
        __syncthreads();
#pragma unroll
        for (int kk = 0; kk < 16; ++kk) {
            float a0 = As[ty][kk], a1 = As[ty + 16][kk];
            float b0 = Bs[kk][tx], b1 = Bs[kk][tx + 16];
            c00 = fmaf(a0, b0, c00); c01 = fmaf(a0, b1, c01);
            c10 = fmaf(a1, b0, c10); c11 = fmaf(a1, b1, c11);
        }
        __syncthreads();
    }
    C[(size_t)(m0 + ty) * Oo + n0 + tx]           = c00;
    C[(size_t)(m0 + ty) * Oo + n0 + tx + 16]      = c01;
    C[(size_t)(m0 + ty + 16) * Oo + n0 + tx]      = c10;
    C[(size_t)(m0 + ty + 16) * Oo + n0 + tx + 16] = c11;
}

// ---------------- generic batched GEMM: C = A * B (or A * B^T), 32x32x16 tiles ----------------
__global__ __launch_bounds__(256) void gemm_g_kernel(
        const float* __restrict__ A, int lda, long long sA,
        const float* __restrict__ Bm, int ldb, long long sB,
        float* __restrict__ C, int ldc, long long sC,
        int K, int transB, const float* __restrict__ bias, int act) {
    int z = blockIdx.z;
    A  += (size_t)z * sA;
    Bm += (size_t)z * sB;
    C  += (size_t)z * sC;
    int tid = threadIdx.x;
    int tx = tid & 15, ty = tid >> 4;
    int m0 = blockIdx.y * 32, n0 = blockIdx.x * 32;
    __shared__ float As[32][17];
    __shared__ float Bs[16][33];
    float c00 = 0.f, c01 = 0.f, c10 = 0.f, c11 = 0.f;
    for (int k0 = 0; k0 < K; k0 += 16) {
        int e = tid, e2 = tid + 256;
        As[e  >> 4][e  & 15] = A[(size_t)(m0 + (e  >> 4)) * lda + k0 + (e  & 15)];
        As[e2 >> 4][e2 & 15] = A[(size_t)(m0 + (e2 >> 4)) * lda + k0 + (e2 & 15)];
        if (!transB) {
            int e3 = tid + 256;
            Bs[tid >> 5][tid & 31] = Bm[(size_t)(k0 + (tid >> 5)) * ldb + n0 + (tid & 31)];
            Bs[e3  >> 5][e3  & 31] = Bm[(size_t)(k0 + (e3  >> 5)) * ldb + n0 + (e3  & 31)];
        } else {
            int n = tid >> 4, k = tid & 15;
            Bs[k][n] = Bm[(size_t)(n0 + n) * ldb + k0 + k];
            int e3 = tid + 256;
            int n2 = e3 >> 4, k2 = e3 & 15;
            Bs[k2][n2] = Bm[(size_t)(n0 + n2) * ldb + k0 + k2];
        }
        __syncthreads();
#pragma unroll
        for (int kk = 0; kk < 16; ++kk) {
            float a0 = As[ty][kk], a1 = As[ty + 16][kk];
            float b0 = Bs[kk][tx], b1 = Bs[kk][tx + 16];
            c00 = fmaf(a0, b0, c00); c01 = fmaf(a0, b1, c01);
            c10 = fmaf(a1, b0, c10); c11 = fmaf(a1, b1, c11);
        }
        __syncthreads();
    }
    float b0v = bias ? bias[n0 + tx] : 0.f;
    float b1v = bias ? bias[n0 + tx + 16] : 0.f;
    c00 += b0v; c01 += b1v; c10 += b0v; c11 += b1v;
    if (act) {
        c00 = fmaxf(c00, 0.f); c01 = fmaxf(c01, 0.f);
        c10 = fmaxf(c10, 0.f); c11 = fmaxf(c11, 0.f);
    }
    C[(size_t)(m0 + ty) * ldc + n0 + tx]           = c00;
    C[(size_t)(m0 + ty) * ldc + n0 + tx + 16]      = c01;
    C[(size_t)(m0 + ty + 16) * ldc + n0 + tx]      = c10;
    C[(size_t)(m0 + ty + 16) * ldc + n0 + tx + 16] = c11;
}

// ---------------- scores: s1[row] = h[row,:]·a[head,:O], s2 = h[row,:]·a[head,O:] ----------------
__global__ __launch_bounds__(256) void scores_kernel(
        const float* __restrict__ h, const float* __restrict__ a,
        float* __restrict__ s1, float* __restrict__ s2, int NperH, int H) {
    int tid = threadIdx.x;
    int lane = tid & 63, wv = tid >> 6;
    long long row = (long long)blockIdx.x * 4 + wv;
    int head = (int)((row / NperH) % H);
    const float* ap = a + (size_t)head * 2 * Oo;
    float4 x4 = ((const float4*)(h + (size_t)row * Oo))[lane];
    float4 a1 = ((const float4*)ap)[lane];
    float4 a2 = ((const float4*)(ap + Oo))[lane];
    float t1 = x4.x * a1.x + x4.y * a1.y + x4.z * a1.z + x4.w * a1.w;
    float t2 = x4.x * a2.x + x4.y * a2.y + x4.z * a2.z + x4.w * a2.w;
    for (int off = 32; off; off >>= 1) {
        t1 += __shfl_down(t1, off, 64);
        t2 += __shfl_down(t2, off, 64);
    }
    if (!lane) { s1[row] = t1; s2[row] = t2; }
}

// ---------------- tiled masked-softmax attention ----------------
// grid (Nn/TI, B*H), 256 threads = 4 waves.
// No max-subtraction (scores are O(±10), exp safe in fp32; softmax shift-invariant).
// Wave covers all 16 ti (lane>>5 selects ti-half of 8) x all 256 o (8 per lane);
// the 4 waves split j 4-way, cross-wave sum via LDS at the end.
__global__ __launch_bounds__(256, 4) void attn2_kernel(
        const float* __restrict__ hsrc, const unsigned* __restrict__ adjbits,
        const float* __restrict__ s1, const float* __restrict__ s2,
        const float* __restrict__ resid, const float* __restrict__ bias,
        float* __restrict__ out, int H, int elu_flag) {
    __shared__ float psT[CJ][16];          // p transposed [jj][ti]
    __shared__ unsigned abits[TI][64];     // adjacency bits for the 16 rows
    __shared__ float s1s[TI];
    __shared__ float lred[16][17];
    __shared__ float linv[TI];
    __shared__ float obuf[TI][Oo];         // cross-wave accumulator (16 KB)

    int i0 = blockIdx.x * TI;
    int bh = blockIdx.y;
    int b  = bh / H, hd = bh - b * H;
    int t  = threadIdx.x;
    int wv = t >> 6, lane = t & 63;
    int og = lane & 31, half = lane >> 5;

    const unsigned* bitbase = adjbits + ((size_t)b * Nn + i0) * 64;
    for (int k = t; k < TI * 64; k += 256) abits[k >> 6][k & 63] = bitbase[k];
    if (t < TI) s1s[t] = s1[(size_t)bh * Nn + i0 + t];
    __syncthreads();

    const float* s2row = s2 + (size_t)bh * Nn;
    const float* hb = hsrc + (size_t)bh * Nn * Oo;

    float acc[8][8];
#pragma unroll
    for (int a = 0; a < 8; ++a)
#pragma unroll
        for (int o = 0; o < 8; ++o) acc[a][o] = 0.f;

    int ti_p = t & 15, jq = t >> 4;        // p-compute mapping
    float s1v = s1s[ti_p];
    float lpart = 0.f;

    for (int c = 0; c < Nn; c += CJ) {
        // compute p for this chunk (all 256 threads)
#pragma unroll
        for (int q = 0; q < CJ / 16; ++q) {
            int jj = jq + 16 * q;
            int j  = c + jj;
            float e = s1v + s2row[j];
            e = e > 0.f ? e : ALPHA_SLOPE * e;
            unsigned w = abits[ti_p][j >> 5];
            float p = ((w >> (j & 31)) & 1u) ? __expf(e) : 0.f;
            psT[jj][ti_p] = p;
            lpart += p;
        }
        __syncthreads();
        // accumulate: wave wv handles jj = wv + 4k
#pragma unroll 2
        for (int k = 0; k < CJ / 4; ++k) {
            int jj = wv + 4 * k;
            float4 p0 = *(const float4*)&psT[jj][half * 8];
            float4 p1 = *(const float4*)&psT[jj][half * 8 + 4];
            bool nz = (p0.x != 0.f) | (p0.y != 0.f) | (p0.z != 0.f) | (p0.w != 0.f) |
                      (p1.x != 0.f) | (p1.y != 0.f) | (p1.z != 0.f) | (p1.w != 0.f);
            if (__ballot(nz)) {
                const float* hrow = hb + (size_t)(c + jj) * Oo + og * 8;
                float4 h0 = *(const float4*)hrow;
                float4 h1 = *(const float4*)(hrow + 4);
                float pa[8] = {p0.x, p0.y, p0.z, p0.w, p1.x, p1.y, p1.z, p1.w};
                float ha[8] = {h0.x, h0.y, h0.z, h0.w, h1.x, h1.y, h1.z, h1.w};
#pragma unroll
                for (int a = 0; a < 8; ++a)
#pragma unroll
                    for (int o = 0; o < 8; ++o)
                        acc[a][o] = fmaf(pa[a], ha[o], acc[a][o]);
            }
        }
        __syncthreads();
    }

    // l reduction (thread's lpart belongs to row ti_p)
    lred[ti_p][jq] = lpart;
    __syncthreads();
    if (t < TI) {
        float s = 0.f;
#pragma unroll
        for (int k = 0; k < 16; ++k) s += lred[t][k];
        linv[t] = 1.f / s;
    }
    // cross-wave accumulator reduction into obuf
    for (int w = 0; w < 4; ++w) {
        if (wv == w) {
#pragma unroll
            for (int a = 0; a < 8; ++a) {
                int ti = half * 8 + a;
                float* ob = &obuf[ti][og * 8];
                if (w == 0) {
#pragma unroll
                    for (int o = 0; o < 8; ++o) ob[o] = acc[a][o];
                } else {
#pragma unroll
                    for (int o = 0; o < 8; ++o) ob[o] += acc[a][o];
                }
            }
        }
        __syncthreads();
    }

    // epilogue: thread t -> row ti = t>>4, float4-group base (t&15), strided by 16
    int ti = t >> 4, c4 = t & 15;
    float li = linv[ti];
    size_t orow = ((size_t)b * Nn + i0 + ti);
#pragma unroll
    for (int rr = 0; rr < 4; ++rr) {
        int o = (c4 + 16 * rr) * 4;
        float4 v = *(const float4*)&obuf[ti][o];
        v.x *= li; v.y *= li; v.z *= li; v.w *= li;
        if (elu_flag) {
            v.x = v.x > 0.f ? v.x : expm1f(v.x);
            v.y = v.y > 0.f ? v.y : expm1f(v.y);
            v.z = v.z > 0.f ? v.z : expm1f(v.z);
            v.w = v.w > 0.f ? v.w : expm1f(v.w);
        }
        if (resid) {
            float4 r = *(const float4*)&resid[orow * Oo + o];
            float4 bi = *(const float4*)&bias[o];
            v.x += r.x + bi.x; v.y += r.y + bi.y;
            v.z += r.z + bi.z; v.w += r.w + bi.w;
        }
        *(float4*)&out[orow * (size_t)(H * Oo) + (size_t)hd * Oo + o] = v;
    }
}

extern "C" void kernel_launch(void* const* d_in, const int* in_sizes, int n_in,
                              void* d_out, int out_size, void* d_ws, size_t ws_size,
                              hipStream_t stream) {
    const float* x       = (const float*)d_in[0];
    const float* adj     = (const float*)d_in[1];
    const float* W_heads = (const float*)d_in[3];
    const float* a_heads = (const float*)d_in[4];
    const float* W_out   = (const float*)d_in[5];
    const float* a_out   = (const float*)d_in[6];
    const float* W_lin   = (const float*)d_in[7];
    const float* b_lin   = (const float*)d_in[8];
    const float* W_ln    = (const float*)d_in[9];
    const float* b_ln    = (const float*)d_in[10];

    float* f   = (float*)d_ws;
    float* s1  = f;                      // [B*H*N]
    float* s2  = f + 32768;
    float* s1b = f + 65536;              // [B*N]
    float* s2b = f + 69632;
    float* x1  = f + 73728;              // [B,N,H*O]
    float* h   = f + 73728 + 8388608;    // [B,H,N,O]
    float* h2  = h;                      // reuse h after multihead attn
    float* lin = h + 1048576;
    float* x2  = h + 2097152;
    unsigned long long* bits = (unsigned long long*)(f + 73728 + 2 * 8388608); // 1 MB

    // 0) adjacency bitmask
    adjbits_kernel<<<(Bb * Nn * Nn) / 256, 256, 0, stream>>>(adj, bits);
    // 1) h = x @ W_heads
    gemm_xw_kernel<<<dim3(Oo / 32, Nn / 32, Bb * Hh), 256, 0, stream>>>(x, W_heads, h);
    // 2) s1, s2
    scores_kernel<<<(Bb * Hh * Nn) / 4, 256, 0, stream>>>(h, a_heads, s1, s2, Nn, Hh);
    // 3) multihead attention + elu -> x1
    attn2_kernel<<<dim3(Nn / TI, Bb * Hh), 256, 0, stream>>>(
        h, (const unsigned*)bits, s1, s2, nullptr, nullptr, x1, Hh, 1);
    // 4) h2 = x1 @ W_out
    gemm_g_kernel<<<dim3(Oo / 32, Nn / 32, Bb), 256, 0, stream>>>(
        x1, Hh * Oo, (long long)Nn * Hh * Oo, W_out, Oo, 0,
        h2, Oo, (long long)Nn * Oo, Hh * Oo, 0, nullptr, 0);
    // 5) lin = x1 @ W_lin^T
    gemm_g_kernel<<<dim3(Oo / 32, Nn / 32, Bb), 256, 0, stream>>>(
        x1, Hh * Oo, (long long)Nn * Hh * Oo, W_lin, Hh * Oo, 0,
        lin, Oo, (long long)Nn * Oo, Hh * Oo, 1, nullptr, 0);
    // 6) s1b, s2b
    scores_kernel<<<(Bb * Nn) / 4, 256, 0, stream>>>(h2, a_out, s1b, s2b, Nn, 1);
    // 7) single-head attention + residual -> x2
    attn2_kernel<<<dim3(Nn / TI, Bb), 256, 0, stream>>>(
        h2, (const unsigned*)bits, s1b, s2b, lin, b_lin, x2, 1, 0);
    // 8) out = relu(x2 @ W_ln^T + b_ln)
    gemm_g_kernel<<<dim3(Oo / 32, Nn / 32, Bb), 256, 0, stream>>>(
        x2, Oo, (long long)Nn * Oo, W_ln, Oo, 0,
        (float*)d_out, Oo, (long long)Nn * Oo, Oo, 1, b_ln, 1);
}

// Round 3
// 553.571 us; speedup vs baseline: 5.8438x; 2.7988x over previous
//
#include <hip/hip_runtime.h>

#define ALPHA_SLOPE 0.2f
constexpr int Bb = 2, Nn = 2048, Ff = 768, Hh = 8, Oo = 256;

typedef __attribute__((ext_vector_type(8)))  short   short8;
typedef __attribute__((ext_vector_type(16))) float   f32x16;
typedef __attribute__((ext_vector_type(4)))  unsigned short ushort4_t;

__device__ inline unsigned short f2bf(float f) {
    unsigned u = __float_as_uint(f);
    u = (u + 0x7FFFu + ((u >> 16) & 1u)) >> 16;   // RNE
    return (unsigned short)u;
}

// ---------------- adjacency bitmask ----------------
__global__ __launch_bounds__(256) void adjbits_kernel(
        const float* __restrict__ adj, unsigned long long* __restrict__ bits) {
    size_t gid = (size_t)blockIdx.x * 256 + threadIdx.x;
    float v = adj[gid];
    unsigned long long m = __ballot(v > 0.f);
    if ((threadIdx.x & 63) == 0) bits[gid >> 6] = m;
}

// ---------------- f32 -> bf16 flat cast (4 per thread) ----------------
__global__ __launch_bounds__(256) void cast_bf_kernel(
        const float* __restrict__ in, unsigned short* __restrict__ out) {
    size_t i = (size_t)blockIdx.x * 256 + threadIdx.x;
    float4 v = ((const float4*)in)[i];
    ushort4_t o;
    o.x = f2bf(v.x); o.y = f2bf(v.y); o.z = f2bf(v.z); o.w = f2bf(v.w);
    ((ushort4_t*)out)[i] = o;
}

// ---------------- [z][R][C] f32 -> [z][C][R] bf16 transpose ----------------
__global__ __launch_bounds__(256) void transpose_bf_kernel(
        const float* __restrict__ in, unsigned short* __restrict__ out, int R, int C) {
    __shared__ float tile[32][33];
    int c0 = blockIdx.x * 32, r0 = blockIdx.y * 32;
    const float* ib = in + (size_t)blockIdx.z * R * C;
    unsigned short* ob = out + (size_t)blockIdx.z * R * C;
    int tx = threadIdx.x & 31, ty = threadIdx.x >> 5;
    for (int k = 0; k < 32; k += 8)
        tile[ty + k][tx] = ib[(size_t)(r0 + ty + k) * C + c0 + tx];
    __syncthreads();
    for (int k = 0; k < 32; k += 8)
        ob[(size_t)(c0 + ty + k) * R + r0 + tx] = f2bf(tile[tx][ty + k]);
}

// ---------------- MFMA GEMM: C[M x 256] = A[M x K] * BT[256 x K]^T ----------------
// block = 64m x 256n, 4 waves (wave = 64m x 64n = 2x2 tiles of 32x32), BK=32.
// A bf16 row-major (k-contig) staged in LDS; B-frags read direct from BT (k-contig).
// mode 0: fp32 C. mode 1: fp32 C + bf16 transposed CT[256][Mtot]. mode 2: bias+relu fp32 C.
__global__ __launch_bounds__(256) void gemm_bf_kernel(
        const unsigned short* __restrict__ A, int K, long long sA, int bAshift,
        const unsigned short* __restrict__ BT, long long sB, int bmask,
        float* __restrict__ C, long long sC,
        unsigned short* __restrict__ CT, long long sCT, int Mtot,
        const float* __restrict__ bias, int mode) {
    int z = blockIdx.z;
    A  += (size_t)(z >> bAshift) * sA;
    BT += (size_t)(z & bmask) * sB;
    C  += (size_t)z * sC;
    if (CT) CT += (size_t)z * sCT;
    int m0 = blockIdx.x * 64;
    int t = threadIdx.x;
    int wv = t >> 6, lane = t & 63;
    int lm = lane & 31, kh = lane >> 5;
    __shared__ unsigned short As[64][40];
    f32x16 acc[2][2] = {};
    int sr = t >> 2, sc = (t & 3) * 8;
    const unsigned short* ag  = A + (size_t)(m0 + sr) * K + sc;
    const unsigned short* bg0 = BT + (size_t)(wv * 64 + lm) * K;
    const unsigned short* bg1 = BT + (size_t)(wv * 64 + 32 + lm) * K;
    for (int k0 = 0; k0 < K; k0 += 32) {
        *(short8*)&As[sr][sc] = *(const short8*)(ag + k0);
        __syncthreads();
#pragma unroll
        for (int ks = 0; ks < 32; ks += 16) {
            short8 a0 = *(const short8*)&As[lm][ks + kh * 8];
            short8 a1 = *(const short8*)&As[32 + lm][ks + kh * 8];
            short8 b0 = *(const short8*)(bg0 + k0 + ks + kh * 8);
            short8 b1 = *(const short8*)(bg1 + k0 + ks + kh * 8);
            acc[0][0] = __builtin_amdgcn_mfma_f32_32x32x16_bf16(a0, b0, acc[0][0], 0, 0, 0);
            acc[0][1] = __builtin_amdgcn_mfma_f32_32x32x16_bf16(a0, b1, acc[0][1], 0, 0, 0);
            acc[1][0] = __builtin_amdgcn_mfma_f32_32x32x16_bf16(a1, b0, acc[1][0], 0, 0, 0);
            acc[1][1] = __builtin_amdgcn_mfma_f32_32x32x16_bf16(a1, b1, acc[1][1], 0, 0, 0);
        }
        __syncthreads();
    }
#pragma unroll
    for (int mt = 0; mt < 2; ++mt)
#pragma unroll
        for (int nt = 0; nt < 2; ++nt) {
            int colg = wv * 64 + nt * 32 + lm;
            float bv = (mode == 2) ? bias[colg] : 0.f;
#pragma unroll
            for (int reg = 0; reg < 16; ++reg) {
                int rl = mt * 32 + 4 * kh + (reg & 3) + 8 * (reg >> 2);
                float v = acc[mt][nt][reg];
                if (mode == 2) { v += bv; v = fmaxf(v, 0.f); }
                C[(size_t)(m0 + rl) * 256 + colg] = v;
            }
            if (mode == 1) {
                unsigned short* ctp = CT + (size_t)colg * Mtot + m0 + mt * 32 + 4 * kh;
#pragma unroll
                for (int q = 0; q < 4; ++q) {
                    ushort4_t pk;
                    pk.x = f2bf(acc[mt][nt][q * 4 + 0]);
                    pk.y = f2bf(acc[mt][nt][q * 4 + 1]);
                    pk.z = f2bf(acc[mt][nt][q * 4 + 2]);
                    pk.w = f2bf(acc[mt][nt][q * 4 + 3]);
                    *(ushort4_t*)(ctp + 8 * q) = pk;
                }
            }
        }
}

// ---------------- scores (fp32 h) ----------------
__global__ __launch_bounds__(256) void scores_kernel(
        const float* __restrict__ h, const float* __restrict__ a,
        float* __restrict__ s1, float* __restrict__ s2, int NperH, int H) {
    int tid = threadIdx.x;
    int lane = tid & 63, wv = tid >> 6;
    long long row = (long long)blockIdx.x * 4 + wv;
    int head = (int)((row / NperH) % H);
    const float* ap = a + (size_t)head * 2 * Oo;
    float4 x4 = ((const float4*)(h + (size_t)row * Oo))[lane];
    float4 a1 = ((const float4*)ap)[lane];
    float4 a2 = ((const float4*)(ap + Oo))[lane];
    float t1 = x4.x * a1.x + x4.y * a1.y + x4.z * a1.z + x4.w * a1.w;
    float t2 = x4.x * a2.x + x4.y * a2.y + x4.z * a2.z + x4.w * a2.w;
    for (int off = 32; off; off >>= 1) {
        t1 += __shfl_down(t1, off, 64);
        t2 += __shfl_down(t2, off, 64);
    }
    if (!lane) { s1[row] = t1; s2[row] = t2; }
}

// ---------------- MFMA attention: out = softmax-mask(P) @ H, 64 i-rows/block ----------------
// A = P (computed -> bf16 LDS), B = hT bf16 [bh][256][2048] (k-contig, direct global).
__global__ __launch_bounds__(256) void attn_mfma_kernel(
        const unsigned short* __restrict__ hT, long long sHT,
        const unsigned* __restrict__ bits,
        const float* __restrict__ s1, const float* __restrict__ s2,
        const float* __restrict__ resid, const float* __restrict__ bias,
        unsigned short* __restrict__ outbf, int ldo,
        int bhshift, int hshift, int elu) {
    int bh = blockIdx.x & ((1 << bhshift) - 1);
    int it = blockIdx.x >> bhshift;
    int b = bh >> hshift, hd = bh & ((1 << hshift) - 1);
    int i0 = it * 64;
    int t = threadIdx.x;
    int wv = t >> 6, lane = t & 63;
    int lm = lane & 31, kh = lane >> 5;

    __shared__ unsigned ab[64 * 64];       // 64 rows x 2048 bits
    __shared__ unsigned short ps[64][72];  // P chunk, bf16, padded
    __shared__ float s1s[64], lred[64][4], linv[64];

    const unsigned* bb = bits + ((size_t)b * Nn + i0) * 64;
    for (int k = t; k < 4096; k += 256) ab[k] = bb[k];
    if (t < 64) s1s[t] = s1[(size_t)bh * Nn + i0 + t];
    __syncthreads();

    int ti = t & 63, jq = t >> 6;
    float s1v = s1s[ti];
    const unsigned* abrow = ab + ti * 64;
    const float* s2row = s2 + (size_t)bh * Nn;
    const unsigned short* hTb = hT + (size_t)bh * sHT;
    const unsigned short* bg0 = hTb + (size_t)(wv * 64 + lm) * Nn;
    const unsigned short* bg1 = hTb + (size_t)(wv * 64 + 32 + lm) * Nn;

    f32x16 acc[2][2] = {};
    float lpart = 0.f;

    for (int c = 0; c < Nn; c += 64) {
#pragma unroll
        for (int u = 0; u < 8; ++u) {
            int jl = jq * 16 + u * 2;
            int j = c + jl;
            float e0 = s1v + s2row[j];
            float e1 = s1v + s2row[j + 1];
            e0 = e0 > 0.f ? e0 : ALPHA_SLOPE * e0;
            e1 = e1 > 0.f ? e1 : ALPHA_SLOPE * e1;
            unsigned w = abrow[j >> 5];
            int sh = j & 31;
            float p0 = ((w >> sh) & 1u) ? __expf(e0) : 0.f;
            float p1 = ((w >> (sh + 1)) & 1u) ? __expf(e1) : 0.f;
            lpart += p0 + p1;
            *(unsigned*)&ps[ti][jl] = (unsigned)f2bf(p0) | ((unsigned)f2bf(p1) << 16);
        }
        __syncthreads();
#pragma unroll
        for (int ks = 0; ks < 64; ks += 16) {
            short8 a0 = *(const short8*)&ps[lm][ks + kh * 8];
            short8 a1 = *(const short8*)&ps[32 + lm][ks + kh * 8];
            short8 b0 = *(const short8*)(bg0 + c + ks + kh * 8);
            short8 b1 = *(const short8*)(bg1 + c + ks + kh * 8);
            acc[0][0] = __builtin_amdgcn_mfma_f32_32x32x16_bf16(a0, b0, acc[0][0], 0, 0, 0);
            acc[0][1] = __builtin_amdgcn_mfma_f32_32x32x16_bf16(a0, b1, acc[0][1], 0, 0, 0);
            acc[1][0] = __builtin_amdgcn_mfma_f32_32x32x16_bf16(a1, b0, acc[1][0], 0, 0, 0);
            acc[1][1] = __builtin_amdgcn_mfma_f32_32x32x16_bf16(a1, b1, acc[1][1], 0, 0, 0);
        }
        __syncthreads();
    }

    lred[ti][jq] = lpart;
    __syncthreads();
    if (t < 64) linv[t] = 1.f / (lred[t][0] + lred[t][1] + lred[t][2] + lred[t][3]);
    __syncthreads();

#pragma unroll
    for (int mt = 0; mt < 2; ++mt)
#pragma unroll
        for (int nt = 0; nt < 2; ++nt) {
            int o = wv * 64 + nt * 32 + lm;
#pragma unroll
            for (int reg = 0; reg < 16; ++reg) {
                int rl = mt * 32 + 4 * kh + (reg & 3) + 8 * (reg >> 2);
                int i = i0 + rl;
                float v = acc[mt][nt][reg] * linv[rl];
                if (elu) v = v > 0.f ? v : expm1f(v);
                if (resid) v += resid[((size_t)b * Nn + i) * Oo + o] + bias[o];
                outbf[((size_t)b * Nn + i) * ldo + (size_t)hd * Oo + o] = f2bf(v);
            }
        }
}

extern "C" void kernel_launch(void* const* d_in, const int* in_sizes, int n_in,
                              void* d_out, int out_size, void* d_ws, size_t ws_size,
                              hipStream_t stream) {
    const float* x       = (const float*)d_in[0];
    const float* adj     = (const float*)d_in[1];
    const float* W_heads = (const float*)d_in[3];
    const float* a_heads = (const float*)d_in[4];
    const float* W_out   = (const float*)d_in[5];
    const float* a_out   = (const float*)d_in[6];
    const float* W_lin   = (const float*)d_in[7];
    const float* b_lin   = (const float*)d_in[8];
    const float* W_ln    = (const float*)d_in[9];
    const float* b_ln    = (const float*)d_in[10];

    char* w = (char*)d_ws;   // ~92.7 MB used
    float* h    = (float*)(w);                         // [16][2048][256] fp32
    float* lin  = (float*)(w + 33554432);              // [2][2048][256]
    float* h2   = (float*)(w + 37748736);              // [2][2048][256]
    float* s1   = (float*)(w + 41943040);
    float* s2   = (float*)(w + 42074112);
    float* s1b  = (float*)(w + 42205184);
    float* s2b  = (float*)(w + 42221568);
    unsigned long long* bits = (unsigned long long*)(w + 42237952);   // 1 MB
    unsigned short* x_bf  = (unsigned short*)(w + 43286528);   // [2][2048][768]
    unsigned short* WhT   = (unsigned short*)(w + 49577984);   // [8][256][768]
    unsigned short* WoT   = (unsigned short*)(w + 52723712);   // [256][2048]
    unsigned short* Wl_bf = (unsigned short*)(w + 53772288);   // [256][2048] (already n-major)
    unsigned short* Wn_bf = (unsigned short*)(w + 54820864);   // [256][256]
    unsigned short* hT    = (unsigned short*)(w + 54951936);   // [16][256][2048]
    unsigned short* h2T   = (unsigned short*)(w + 71729152);   // [2][256][2048]
    unsigned short* x1_bf = (unsigned short*)(w + 73826304);   // [2][2048][2048]
    unsigned short* x2_bf = (unsigned short*)(w + 90603520);   // [2][2048][256]

    // 0) precompute: bitmask, bf16 casts, weight transposes
    adjbits_kernel<<<(Bb * Nn * Nn) / 256, 256, 0, stream>>>(adj, bits);
    cast_bf_kernel<<<(Bb * Nn * Ff) / 1024, 256, 0, stream>>>(x, x_bf);
    cast_bf_kernel<<<(Oo * Hh * Oo) / 1024, 256, 0, stream>>>(W_lin, Wl_bf);
    cast_bf_kernel<<<(Oo * Oo) / 1024, 256, 0, stream>>>(W_ln, Wn_bf);
    transpose_bf_kernel<<<dim3(Oo / 32, Ff / 32, Hh), 256, 0, stream>>>(W_heads, WhT, Ff, Oo);
    transpose_bf_kernel<<<dim3(Oo / 32, (Hh * Oo) / 32, 1), 256, 0, stream>>>(W_out, WoT, Hh * Oo, Oo);

    // 1) h = x @ W_heads  (z = b*8+hd), also hT bf16
    gemm_bf_kernel<<<dim3(Nn / 64, 1, Bb * Hh), 256, 0, stream>>>(
        x_bf, Ff, (long long)Nn * Ff, 3, WhT, (long long)Ff * Oo, 7,
        h, (long long)Nn * Oo, hT, (long long)Nn * Oo, Nn, nullptr, 1);
    // 2) s1, s2
    scores_kernel<<<(Bb * Hh * Nn) / 4, 256, 0, stream>>>(h, a_heads, s1, s2, Nn, Hh);
    // 3) multihead attention + elu -> x1_bf [B][N][2048]
    attn_mfma_kernel<<<dim3((Bb * Hh) * (Nn / 64)), 256, 0, stream>>>(
        hT, (long long)Oo * Nn, (const unsigned*)bits, s1, s2,
        nullptr, nullptr, x1_bf, Hh * Oo, 4, 3, 1);
    // 4) h2 = x1 @ W_out (+ h2T bf16)
    gemm_bf_kernel<<<dim3(Nn / 64, 1, Bb), 256, 0, stream>>>(
        x1_bf, Hh * Oo, (long long)Nn * Hh * Oo, 0, WoT, 0, 0,
        h2, (long long)Nn * Oo, h2T, (long long)Nn * Oo, Nn, nullptr, 1);
    // 5) lin = x1 @ W_lin^T (fp32 only)
    gemm_bf_kernel<<<dim3(Nn / 64, 1, Bb), 256, 0, stream>>>(
        x1_bf, Hh * Oo, (long long)Nn * Hh * Oo, 0, Wl_bf, 0, 0,
        lin, (long long)Nn * Oo, nullptr, 0, Nn, nullptr, 0);
    // 6) layer-2 scores
    scores_kernel<<<(Bb * Nn) / 4, 256, 0, stream>>>(h2, a_out, s1b, s2b, Nn, 1);
    // 7) single-head attention + resid(lin)+b_lin -> x2_bf [B][N][256]
    attn_mfma_kernel<<<dim3(Bb * (Nn / 64)), 256, 0, stream>>>(
        h2T, (long long)Oo * Nn, (const unsigned*)bits, s1b, s2b,
        lin, b_lin, x2_bf, Oo, 1, 0, 0);
    // 8) out = relu(x2 @ W_ln^T + b_ln)
    gemm_bf_kernel<<<dim3(Nn / 64, 1, Bb), 256, 0, stream>>>(
        x2_bf, Oo, (long long)Nn * Oo, 0, Wn_bf, 0, 0,
        (float*)d_out, (long long)Nn * Oo, nullptr, 0, Nn, b_ln, 2);
}

// Round 5
// 422.715 us; speedup vs baseline: 7.6529x; 1.3096x over previous
//
#include <hip/hip_runtime.h>
#include <hip/hip_bf16.h>

constexpr int Bb = 2, Nn = 2048, Ff = 768, Hh = 8, Oo = 256;

typedef __attribute__((ext_vector_type(8)))  short   short8;
typedef __attribute__((ext_vector_type(16))) float   f32x16;
typedef __attribute__((ext_vector_type(4)))  unsigned short ushort4_t;

__device__ inline unsigned short f2bf(float f) {
    unsigned u = __float_as_uint(f);
    u = (u + 0x7FFFu + ((u >> 16) & 1u)) >> 16;   // RNE
    return (unsigned short)u;
}

// ---------------- adjacency bitmask ----------------
__global__ __launch_bounds__(256) void adjbits_kernel(
        const float* __restrict__ adj, unsigned long long* __restrict__ bits) {
    size_t gid = (size_t)blockIdx.x * 256 + threadIdx.x;
    float v = adj[gid];
    unsigned long long m = __ballot(v > 0.f);
    if ((threadIdx.x & 63) == 0) bits[gid >> 6] = m;
}

// ---------------- f32 -> bf16 flat cast ----------------
__global__ __launch_bounds__(256) void cast_bf_kernel(
        const float* __restrict__ in, unsigned short* __restrict__ out) {
    size_t i = (size_t)blockIdx.x * 256 + threadIdx.x;
    float4 v = ((const float4*)in)[i];
    ushort4_t o;
    o.x = f2bf(v.x); o.y = f2bf(v.y); o.z = f2bf(v.z); o.w = f2bf(v.w);
    ((ushort4_t*)out)[i] = o;
}

// ---------------- [z][R][C] f32 -> [z][C][R] bf16 transpose ----------------
__global__ __launch_bounds__(256) void transpose_bf_kernel(
        const float* __restrict__ in, unsigned short* __restrict__ out, int R, int C) {
    __shared__ float tile[32][33];
    int c0 = blockIdx.x * 32, r0 = blockIdx.y * 32;
    const float* ib = in + (size_t)blockIdx.z * R * C;
    unsigned short* ob = out + (size_t)blockIdx.z * R * C;
    int tx = threadIdx.x & 31, ty = threadIdx.x >> 5;
    for (int k = 0; k < 32; k += 8)
        tile[ty + k][tx] = ib[(size_t)(r0 + ty + k) * C + c0 + tx];
    __syncthreads();
    for (int k = 0; k < 32; k += 8)
        ob[(size_t)(c0 + ty + k) * R + r0 + tx] = f2bf(tile[tx][ty + k]);
}

// ---------------- MFMA GEMM: C[M x 256] = A[M x K] * BT[256 x K]^T ----------------
__global__ __launch_bounds__(256) void gemm_bf_kernel(
        const unsigned short* __restrict__ A, int K, long long sA, int bAshift,
        const unsigned short* __restrict__ BT, long long sB, int bmask,
        float* __restrict__ C, long long sC,
        unsigned short* __restrict__ CT, long long sCT, int Mtot,
        const float* __restrict__ bias, int mode) {
    int z = blockIdx.z;
    A  += (size_t)(z >> bAshift) * sA;
    BT += (size_t)(z & bmask) * sB;
    C  += (size_t)z * sC;
    if (CT) CT += (size_t)z * sCT;
    int m0 = blockIdx.x * 64;
    int t = threadIdx.x;
    int wv = t >> 6, lane = t & 63;
    int lm = lane & 31, kh = lane >> 5;
    __shared__ unsigned short As[64][40];
    f32x16 acc[2][2] = {};
    int sr = t >> 2, sc = (t & 3) * 8;
    const unsigned short* ag  = A + (size_t)(m0 + sr) * K + sc;
    const unsigned short* bg0 = BT + (size_t)(wv * 64 + lm) * K;
    const unsigned short* bg1 = BT + (size_t)(wv * 64 + 32 + lm) * K;
    for (int k0 = 0; k0 < K; k0 += 32) {
        *(short8*)&As[sr][sc] = *(const short8*)(ag + k0);
        __syncthreads();
#pragma unroll
        for (int ks = 0; ks < 32; ks += 16) {
            short8 a0 = *(const short8*)&As[lm][ks + kh * 8];
            short8 a1 = *(const short8*)&As[32 + lm][ks + kh * 8];
            short8 b0 = *(const short8*)(bg0 + k0 + ks + kh * 8);
            short8 b1 = *(const short8*)(bg1 + k0 + ks + kh * 8);
            acc[0][0] = __builtin_amdgcn_mfma_f32_32x32x16_bf16(a0, b0, acc[0][0], 0, 0, 0);
            acc[0][1] = __builtin_amdgcn_mfma_f32_32x32x16_bf16(a0, b1, acc[0][1], 0, 0, 0);
            acc[1][0] = __builtin_amdgcn_mfma_f32_32x32x16_bf16(a1, b0, acc[1][0], 0, 0, 0);
            acc[1][1] = __builtin_amdgcn_mfma_f32_32x32x16_bf16(a1, b1, acc[1][1], 0, 0, 0);
        }
        __syncthreads();
    }
#pragma unroll
    for (int mt = 0; mt < 2; ++mt)
#pragma unroll
        for (int nt = 0; nt < 2; ++nt) {
            int colg = wv * 64 + nt * 32 + lm;
            float bv = (mode == 2) ? bias[colg] : 0.f;
#pragma unroll
            for (int reg = 0; reg < 16; ++reg) {
                int rl = mt * 32 + 4 * kh + (reg & 3) + 8 * (reg >> 2);
                float v = acc[mt][nt][reg];
                if (mode == 2) { v += bv; v = fmaxf(v, 0.f); }
                C[(size_t)(m0 + rl) * 256 + colg] = v;
            }
            if (mode == 1) {
                unsigned short* ctp = CT + (size_t)colg * Mtot + m0 + mt * 32 + 4 * kh;
#pragma unroll
                for (int q = 0; q < 4; ++q) {
                    ushort4_t pk;
                    pk.x = f2bf(acc[mt][nt][q * 4 + 0]);
                    pk.y = f2bf(acc[mt][nt][q * 4 + 1]);
                    pk.z = f2bf(acc[mt][nt][q * 4 + 2]);
                    pk.w = f2bf(acc[mt][nt][q * 4 + 3]);
                    *(ushort4_t*)(ctp + 8 * q) = pk;
                }
            }
        }
}

// ---------------- scores + exp factors ----------------
__global__ __launch_bounds__(256) void scores_exp_kernel(
        const float* __restrict__ h, const float* __restrict__ a,
        float* __restrict__ E1p, float* __restrict__ E1n,
        float2* __restrict__ E2pn, int NperH, int H) {
    int tid = threadIdx.x;
    int lane = tid & 63, wv = tid >> 6;
    long long row = (long long)blockIdx.x * 4 + wv;
    int head = (int)((row / NperH) % H);
    const float* ap = a + (size_t)head * 2 * Oo;
    float4 x4 = ((const float4*)(h + (size_t)row * Oo))[lane];
    float4 a1 = ((const float4*)ap)[lane];
    float4 a2 = ((const float4*)(ap + Oo))[lane];
    float t1 = x4.x * a1.x + x4.y * a1.y + x4.z * a1.z + x4.w * a1.w;
    float t2 = x4.x * a2.x + x4.y * a2.y + x4.z * a2.z + x4.w * a2.w;
    for (int off = 32; off; off >>= 1) {
        t1 += __shfl_down(t1, off, 64);
        t2 += __shfl_down(t2, off, 64);
    }
    if (!lane) {
        E1p[row] = __expf(t1);
        E1n[row] = __expf(0.2f * t1);
        E2pn[row] = make_float2(__expf(t2), __expf(0.2f * t2));
    }
}

// ---------------- pipelined MFMA attention ----------------
// MODE 0: direct (elu, bf16 out).  MODE 1: partial over j-range (f32 acc + l).
template<int JLEN, int MODE>
__global__ __launch_bounds__(256, 2) void attn_v2_kernel(
        const unsigned short* __restrict__ hT, long long sHT,
        const unsigned* __restrict__ bits,
        const float* __restrict__ E1p, const float* __restrict__ E1n,
        const float2* __restrict__ E2pn,
        unsigned short* __restrict__ outbf, int ldo,
        float* __restrict__ pacc, float* __restrict__ plsum,
        int hshift) {
    constexpr int W = JLEN / 32, NC = JLEN / 64, ABS = W + 1;
    int it = blockIdx.x, bh = blockIdx.y, js = blockIdx.z;
    int b = bh >> hshift, hd = bh & ((1 << hshift) - 1);
    int i0 = it * 64, jbase = js * JLEN;
    int t = threadIdx.x, lane = t & 63;
    int wv = t >> 6, lm = lane & 31, kh = lane >> 5;
    int ti = lane, jq = wv;

    __shared__ unsigned ab[64 * ABS];
    __shared__ __align__(16) unsigned short ps[2][64][64];
    __shared__ float lred[64][5];
    __shared__ float linv[64];

    const unsigned* bb = bits + ((size_t)b * Nn + i0) * 64 + (jbase >> 5);
    for (int k = t; k < 64 * W; k += 256) {
        int r = k / W, w0 = k - r * W;
        ab[r * ABS + w0] = bb[(size_t)r * 64 + w0];
    }
    __syncthreads();   // <<< FIX: ab[] staged by other threads must be visible before computeP

    float e1p = E1p[(size_t)bh * Nn + i0 + ti];
    float e1n = E1n[(size_t)bh * Nn + i0 + ti];
    const float4* e2base = (const float4*)(E2pn + (size_t)bh * Nn + jbase);

    const unsigned short* hTb = hT + (size_t)bh * sHT + jbase;
    const unsigned short* bg0 = hTb + (size_t)(wv * 64 + lm) * Nn;
    const unsigned short* bg1 = hTb + (size_t)(wv * 64 + 32 + lm) * Nn;

    f32x16 acc[2][2] = {};
    float lpart = 0.f;
    short8 B0[8], B1[8];

    auto loadB = [&](int c, short8* B) {
#pragma unroll
        for (int s = 0; s < 4; ++s) {
            B[2 * s]     = *(const short8*)(bg0 + c * 64 + s * 16 + kh * 8);
            B[2 * s + 1] = *(const short8*)(bg1 + c * 64 + s * 16 + kh * 8);
        }
    };
    auto computeP = [&](int c, int buf) {
        int cj = c * 64;
        unsigned word = ab[ti * ABS + ((cj >> 5) + (jq >> 1))];
        unsigned field = word >> ((jq & 1) * 16);
        const float4* ep = e2base + ((cj + jq * 16) >> 1);
        unsigned pk[8];
#pragma unroll
        for (int u = 0; u < 8; ++u) {
            float4 q = ep[u];
            float pp0 = e1p * q.x, pn0 = e1n * q.y;
            float p0 = pp0 > 1.f ? pp0 : pn0;
            p0 = ((field >> (2 * u)) & 1u) ? p0 : 0.f;
            float pp1 = e1p * q.z, pn1 = e1n * q.w;
            float p1 = pp1 > 1.f ? pp1 : pn1;
            p1 = ((field >> (2 * u + 1)) & 1u) ? p1 : 0.f;
            lpart += p0 + p1;
            __hip_bfloat162 hv = __float22bfloat162_rn(make_float2(p0, p1));
            pk[u] = *(unsigned*)&hv;
        }
        unsigned sw = ti & 7;
        uint4 v0; v0.x = pk[0]; v0.y = pk[1]; v0.z = pk[2]; v0.w = pk[3];
        uint4 v1; v1.x = pk[4]; v1.y = pk[5]; v1.z = pk[6]; v1.w = pk[7];
        *(uint4*)&ps[buf][ti][((2 * jq) ^ sw) * 8]     = v0;
        *(uint4*)&ps[buf][ti][((2 * jq + 1) ^ sw) * 8] = v1;
    };
    auto mfmaStep = [&](int buf, short8* B) {
        unsigned sw = lm & 7;
#pragma unroll
        for (int s = 0; s < 4; ++s) {
            short8 a0 = *(const short8*)&ps[buf][lm][((2 * s + kh) ^ sw) * 8];
            short8 a1 = *(const short8*)&ps[buf][32 + lm][((2 * s + kh) ^ sw) * 8];
            acc[0][0] = __builtin_amdgcn_mfma_f32_32x32x16_bf16(a0, B[2 * s],     acc[0][0], 0, 0, 0);
            acc[0][1] = __builtin_amdgcn_mfma_f32_32x32x16_bf16(a0, B[2 * s + 1], acc[0][1], 0, 0, 0);
            acc[1][0] = __builtin_amdgcn_mfma_f32_32x32x16_bf16(a1, B[2 * s],     acc[1][0], 0, 0, 0);
            acc[1][1] = __builtin_amdgcn_mfma_f32_32x32x16_bf16(a1, B[2 * s + 1], acc[1][1], 0, 0, 0);
        }
    };

    loadB(0, B0);
    computeP(0, 0);
    __syncthreads();
    for (int c = 0; c < NC; c += 2) {
        loadB(c + 1, B1);
        mfmaStep(0, B0);
        computeP(c + 1, 1);
        __syncthreads();
        if (c + 2 < NC) loadB(c + 2, B0);
        mfmaStep(1, B1);
        if (c + 2 < NC) computeP(c + 2, 0);
        __syncthreads();
    }

    lred[ti][jq] = lpart;
    __syncthreads();
    if (MODE == 0) {
        if (t < 64) linv[t] = 1.f / (lred[t][0] + lred[t][1] + lred[t][2] + lred[t][3]);
        __syncthreads();
#pragma unroll
        for (int mt = 0; mt < 2; ++mt)
#pragma unroll
            for (int nt = 0; nt < 2; ++nt) {
                int o = wv * 64 + nt * 32 + lm;
#pragma unroll
                for (int reg = 0; reg < 16; ++reg) {
                    int rl = mt * 32 + 4 * kh + (reg & 3) + 8 * (reg >> 2);
                    float v = acc[mt][nt][reg] * linv[rl];
                    v = v > 0.f ? v : expm1f(v);   // elu (direct mode = layer 1)
                    outbf[((size_t)b * Nn + i0 + rl) * ldo + (size_t)hd * Oo + o] = f2bf(v);
                }
            }
    } else {
        if (t < 64)
            plsum[((size_t)js * Bb + b) * Nn + i0 + t] =
                lred[t][0] + lred[t][1] + lred[t][2] + lred[t][3];
        float* pa = pacc + (((size_t)js * Bb + b) * Nn) * 256;
#pragma unroll
        for (int mt = 0; mt < 2; ++mt)
#pragma unroll
            for (int nt = 0; nt < 2; ++nt) {
                int o = wv * 64 + nt * 32 + lm;
#pragma unroll
                for (int reg = 0; reg < 16; ++reg) {
                    int rl = mt * 32 + 4 * kh + (reg & 3) + 8 * (reg >> 2);
                    pa[(size_t)(i0 + rl) * 256 + o] = acc[mt][nt][reg];
                }
            }
    }
}

// ---------------- combine partials (single-head layer): x2 = Σacc/Σl + lin + b ----------------
__global__ __launch_bounds__(256) void combine_kernel(
        const float* __restrict__ pacc, const float* __restrict__ plsum,
        const float* __restrict__ lin, const float* __restrict__ bias,
        unsigned short* __restrict__ out) {
    int gid = blockIdx.x * 256 + threadIdx.x;   // per float4; total B*N*64
    int row = gid >> 6;
    int o4 = gid & 63;
    size_t ps4 = (size_t)Bb * Nn * 64;
    const float4* p = (const float4*)pacc + (size_t)row * 64 + o4;
    float4 s = p[0], sa = p[ps4], sb = p[2 * ps4], sc = p[3 * ps4];
    s.x += sa.x + sb.x + sc.x; s.y += sa.y + sb.y + sc.y;
    s.z += sa.z + sb.z + sc.z; s.w += sa.w + sb.w + sc.w;
    int BN = Bb * Nn;
    float li = 1.f / (plsum[row] + plsum[row + BN] + plsum[row + 2 * BN] + plsum[row + 3 * BN]);
    float4 lv = ((const float4*)lin)[(size_t)row * 64 + o4];
    float4 bv = ((const float4*)bias)[o4];
    float4 v;
    v.x = s.x * li + lv.x + bv.x; v.y = s.y * li + lv.y + bv.y;
    v.z = s.z * li + lv.z + bv.z; v.w = s.w * li + lv.w + bv.w;
    __hip_bfloat162 h0 = __float22bfloat162_rn(make_float2(v.x, v.y));
    __hip_bfloat162 h1 = __float22bfloat162_rn(make_float2(v.z, v.w));
    uint2 st; st.x = *(unsigned*)&h0; st.y = *(unsigned*)&h1;
    *(uint2*)(out + (size_t)gid * 4) = st;
}

extern "C" void kernel_launch(void* const* d_in, const int* in_sizes, int n_in,
                              void* d_out, int out_size, void* d_ws, size_t ws_size,
                              hipStream_t stream) {
    const float* x       = (const float*)d_in[0];
    const float* adj     = (const float*)d_in[1];
    const float* W_heads = (const float*)d_in[3];
    const float* a_heads = (const float*)d_in[4];
    const float* W_out   = (const float*)d_in[5];
    const float* a_out   = (const float*)d_in[6];
    const float* W_lin   = (const float*)d_in[7];
    const float* b_lin   = (const float*)d_in[8];
    const float* W_ln    = (const float*)d_in[9];
    const float* b_ln    = (const float*)d_in[10];

    char* w = (char*)d_ws;   // ~90.9 MB
    float* h        = (float*)(w);                    // [16][2048][256] f32 (dead after scores_mh; reused for sh partials)
    float* lin      = (float*)(w + 33554432);         // [2][2048][256]
    float* h2       = (float*)(w + 37748736);         // [2][2048][256]
    float* E1p_mh   = (float*)(w + 41943040);
    float* E1n_mh   = (float*)(w + 42074112);
    float2* E2pn_mh = (float2*)(w + 42205184);
    float* E1p_sh   = (float*)(w + 42467328);
    float* E1n_sh   = (float*)(w + 42483712);
    float2* E2pn_sh = (float2*)(w + 42500096);
    unsigned long long* bits = (unsigned long long*)(w + 42532864);   // 1 MB
    unsigned short* x_bf  = (unsigned short*)(w + 43581440);   // [2][2048][768] (dead after gemm1)
    unsigned short* x2_bf = (unsigned short*)(w + 43581440);   // reuse x_bf region
    unsigned short* WhT   = (unsigned short*)(w + 49872896);   // [8][256][768]
    unsigned short* WoT   = (unsigned short*)(w + 53018624);   // [256][2048]
    unsigned short* Wl_bf = (unsigned short*)(w + 54067200);   // [256][2048]
    unsigned short* Wn_bf = (unsigned short*)(w + 55115776);   // [256][256]
    unsigned short* hT    = (unsigned short*)(w + 55246848);   // [16][256][2048]
    unsigned short* h2T   = (unsigned short*)(w + 72024064);   // [2][256][2048]
    unsigned short* x1_bf = (unsigned short*)(w + 74121216);   // [2][2048][2048]
    float* pacc  = h;                                          // 4x[2][2048][256] f32 = 16 MB
    float* plsum = h + 4194304;                                // 4x[2][2048]

    // 0) prep
    adjbits_kernel<<<(Bb * Nn * Nn) / 256, 256, 0, stream>>>(adj, bits);
    cast_bf_kernel<<<(Bb * Nn * Ff) / 1024, 256, 0, stream>>>(x, x_bf);
    cast_bf_kernel<<<(Oo * Hh * Oo) / 1024, 256, 0, stream>>>(W_lin, Wl_bf);
    cast_bf_kernel<<<(Oo * Oo) / 1024, 256, 0, stream>>>(W_ln, Wn_bf);
    transpose_bf_kernel<<<dim3(Oo / 32, Ff / 32, Hh), 256, 0, stream>>>(W_heads, WhT, Ff, Oo);
    transpose_bf_kernel<<<dim3(Oo / 32, (Hh * Oo) / 32, 1), 256, 0, stream>>>(W_out, WoT, Hh * Oo, Oo);

    // 1) h = x @ W_heads (+ hT bf16)
    gemm_bf_kernel<<<dim3(Nn / 64, 1, Bb * Hh), 256, 0, stream>>>(
        x_bf, Ff, (long long)Nn * Ff, 3, WhT, (long long)Ff * Oo, 7,
        h, (long long)Nn * Oo, hT, (long long)Nn * Oo, Nn, nullptr, 1);
    // 2) scores + exp factors (mh)
    scores_exp_kernel<<<(Bb * Hh * Nn) / 4, 256, 0, stream>>>(h, a_heads, E1p_mh, E1n_mh, E2pn_mh, Nn, Hh);
    // 3) multihead attention + elu -> x1_bf
    attn_v2_kernel<2048, 0><<<dim3(Nn / 64, Bb * Hh, 1), 256, 0, stream>>>(
        hT, (long long)Oo * Nn, (const unsigned*)bits, E1p_mh, E1n_mh, E2pn_mh,
        x1_bf, Hh * Oo, nullptr, nullptr, 3);
    // 4) h2 = x1 @ W_out (+ h2T bf16)
    gemm_bf_kernel<<<dim3(Nn / 64, 1, Bb), 256, 0, stream>>>(
        x1_bf, Hh * Oo, (long long)Nn * Hh * Oo, 0, WoT, 0, 0,
        h2, (long long)Nn * Oo, h2T, (long long)Nn * Oo, Nn, nullptr, 1);
    // 5) lin = x1 @ W_lin^T
    gemm_bf_kernel<<<dim3(Nn / 64, 1, Bb), 256, 0, stream>>>(
        x1_bf, Hh * Oo, (long long)Nn * Hh * Oo, 0, Wl_bf, 0, 0,
        lin, (long long)Nn * Oo, nullptr, 0, Nn, nullptr, 0);
    // 6) scores + exp factors (sh)
    scores_exp_kernel<<<(Bb * Nn) / 4, 256, 0, stream>>>(h2, a_out, E1p_sh, E1n_sh, E2pn_sh, Nn, 1);
    // 7) single-head attention, j-split partials
    attn_v2_kernel<512, 1><<<dim3(Nn / 64, Bb, 4), 256, 0, stream>>>(
        h2T, (long long)Oo * Nn, (const unsigned*)bits, E1p_sh, E1n_sh, E2pn_sh,
        nullptr, 0, pacc, plsum, 0);
    // 8) combine -> x2_bf
    combine_kernel<<<(Bb * Nn * 64) / 256, 256, 0, stream>>>(pacc, plsum, lin, b_lin, x2_bf);
    // 9) out = relu(x2 @ W_ln^T + b_ln)
    gemm_bf_kernel<<<dim3(Nn / 64, 1, Bb), 256, 0, stream>>>(
        x2_bf, Oo, (long long)Nn * Oo, 0, Wn_bf, 0, 0,
        (float*)d_out, (long long)Nn * Oo, nullptr, 0, Nn, b_ln, 2);
}